// Round 10
// baseline (167.170 us; speedup 1.0000x reference)
//
#include <hip/hip_runtime.h>
#include <hip/hip_fp16.h>

// Problem constants (fixed by reference)
#define BB 8
#define NN 1024
#define HH 768
#define NHEAD 12
#define HD 64
#define NSEG 8192            // B*N
#define QKVN 2304            // 3*H
#define MAXDEG 64            // bucket capacity per segment (Poisson(16); P(>64) ~ 1e-18)

typedef unsigned short u16;
typedef __attribute__((ext_vector_type(8))) _Float16 f16x8;
typedef __attribute__((ext_vector_type(4))) float f32x4;
typedef __attribute__((ext_vector_type(4))) unsigned int u32x4;
typedef __attribute__((ext_vector_type(2))) unsigned int u32x2;

__device__ __forceinline__ u16 f2h(float f) {
  _Float16 h = (_Float16)f;
  return __builtin_bit_cast(u16, h);
}
__device__ __forceinline__ __half2 h2(unsigned int w) {
  return __builtin_bit_cast(__half2, w);
}

// ---------------- fused prep: cast X, transpose W, build CSR ----------------
#define CAST_BLKS (NSEG * HH / 4 / 256)     // 6144
#define TW_BLKS   ((QKVN / 32) * (HH / 32)) // 1728
#define BUILD_BLKS 512

__global__ void prep_kernel(const float* __restrict__ X, u16* __restrict__ Xb,
                            const float* __restrict__ Wq, const float* __restrict__ Wk,
                            const float* __restrict__ Wv, u16* __restrict__ Wt,
                            const int* __restrict__ EI, int* __restrict__ cursor,
                            int* __restrict__ tailrow, int E) {
  const int bid = blockIdx.x;
  if (bid < CAST_BLKS) {
    int i = bid * 256 + threadIdx.x;
    float4 f = ((const float4*)X)[i];
    ushort4 o;
    o.x = f2h(f.x); o.y = f2h(f.y); o.z = f2h(f.z); o.w = f2h(f.w);
    ((ushort4*)Xb)[i] = o;
  } else if (bid < CAST_BLKS + TW_BLKS) {
    __shared__ float tile[32][33];
    int t = bid - CAST_BLKS;
    int n0 = (t % (QKVN / 32)) * 32;
    int k0 = (t / (QKVN / 32)) * 32;
    const float* W = (n0 < HH) ? Wq : (n0 < 2 * HH ? Wk : Wv);
    int nb = n0 - (n0 < HH ? 0 : (n0 < 2 * HH ? HH : 2 * HH));
    int tx = threadIdx.x & 31, ty = threadIdx.x >> 5;   // (32, 8)
#pragma unroll
    for (int r = 0; r < 4; ++r)
      tile[ty + 8 * r][tx] = W[(k0 + ty + 8 * r) * HH + nb + tx];
    __syncthreads();
#pragma unroll
    for (int r = 0; r < 4; ++r)
      Wt[(n0 + ty + 8 * r) * HH + k0 + tx] = f2h(tile[tx][ty + 8 * r]);
  } else {
    int e = (bid - CAST_BLKS - TW_BLKS) * 256 + threadIdx.x;
    if (e >= E) return;
    int b = EI[e];
    int seg = b * NN + EI[E + e];
    int j = EI[2 * E + e];
    int pos = atomicAdd(&cursor[seg], 1);
    if (pos < MAXDEG) tailrow[seg * MAXDEG + pos] = b * NN + j;
  }
}

// ---------------- fused QKV GEMM: (8192x768) @ (768x2304), f16 MFMA ----------------
// R6 depth-2 pipeline (3 bufs, s_barrier + vmcnt(4)); R9 XOR bank-swizzle.
// R10: 1D grid with XCD-affinity swizzle — XCD x (= bid&7 under round-robin
// dispatch) owns m-tiles [8x, 8x+8): its Xb slice (1.6 MB) stays L2-resident
// across all 18 n-tiles instead of thrashing.
#define BM 128
#define BN 128
#define BK 32
#define NITER (HH / BK)   // 24

__global__ __launch_bounds__(256) void gemm_kernel(const u16* __restrict__ Xb,
                                                   const u16* __restrict__ Wt,
                                                   u16* __restrict__ QKV) {
  __shared__ u16 As[3][BM * BK];   // 3 x 8 KB
  __shared__ u16 Bs[3][BN * BK];   // 3 x 8 KB
  const int tid = threadIdx.x;
  const int wave = tid >> 6;
  const int lane = tid & 63;
  const int bid = blockIdx.x;      // 0..1151
  const int mt = (bid & 7) * 8 + ((bid >> 3) & 7);   // m-tile 0..63, XCD-grouped
  const int nt = bid >> 6;                            // n-tile 0..17
  const int m0 = mt * BM;
  const int n0 = nt * BN;
  const int wr = wave >> 1;
  const int wc = wave & 1;
  const int quad = lane >> 4;
  const int l15 = lane & 15;

  f32x4 acc[4][4] = {};

  const int srow = wave * 16 + (lane >> 2);
  const int scol = (((lane & 3) ^ ((lane >> 3) & 3)) << 3);   // swizzled k-quad fetch
  const int rswz = quad ^ ((l15 >> 1) & 3);                    // read-side swizzle

  auto stage = [&](int buf, int kt) {
#pragma unroll
    for (int p = 0; p < 2; ++p) {
      const u16* ga = Xb + (m0 + p * 64 + srow) * HH + kt + scol;
      const u16* gb = Wt + (n0 + p * 64 + srow) * HH + kt + scol;
      u16* la = As[buf] + p * 2048 + wave * 512;
      u16* lb = Bs[buf] + p * 2048 + wave * 512;
      __builtin_amdgcn_global_load_lds(
          (const __attribute__((address_space(1))) unsigned int*)(unsigned long long)ga,
          (__attribute__((address_space(3))) unsigned int*)(unsigned long long)la, 16, 0, 0);
      __builtin_amdgcn_global_load_lds(
          (const __attribute__((address_space(1))) unsigned int*)(unsigned long long)gb,
          (__attribute__((address_space(3))) unsigned int*)(unsigned long long)lb, 16, 0, 0);
    }
  };

  stage(0, 0);
  stage(1, BK);

#pragma unroll 3
  for (int it = 0; it < NITER; ++it) {
    if (it != NITER - 1) {
      asm volatile("s_waitcnt vmcnt(4)" ::: "memory");
    } else {
      asm volatile("s_waitcnt vmcnt(0)" ::: "memory");
    }
    asm volatile("s_barrier" ::: "memory");
    if (it + 2 < NITER) stage((it + 2) % 3, (it + 2) * BK);

    const int b = it % 3;
    f16x8 afr[4], bfr[4];
#pragma unroll
    for (int mi = 0; mi < 4; ++mi) {
      int m = wr * 64 + mi * 16 + l15;
      afr[mi] = *(const f16x8*)(As[b] + m * BK + rswz * 8);
    }
#pragma unroll
    for (int ni = 0; ni < 4; ++ni) {
      int n = wc * 64 + ni * 16 + l15;
      bfr[ni] = *(const f16x8*)(Bs[b] + n * BK + rswz * 8);
    }
#pragma unroll
    for (int mi = 0; mi < 4; ++mi)
#pragma unroll
      for (int ni = 0; ni < 4; ++ni)
        acc[mi][ni] = __builtin_amdgcn_mfma_f32_16x16x32_f16(afr[mi], bfr[ni], acc[mi][ni], 0, 0, 0);
  }

  // epilogue: C/D layout col=lane&15, row=(lane>>4)*4+reg  [m89-verified]
#pragma unroll
  for (int mi = 0; mi < 4; ++mi)
#pragma unroll
    for (int ni = 0; ni < 4; ++ni) {
      int col = n0 + wc * 64 + ni * 16 + l15;
#pragma unroll
      for (int r = 0; r < 4; ++r) {
        int row = m0 + wr * 64 + mi * 16 + quad * 4 + r;
        QKV[row * QKVN + col] = f2h(acc[mi][ni][r]);
      }
    }
}

// ---------------- attention: 2 waves/segment, idx-preload + depth-2 prefetch ----------------
// Lane mapping (R2-verified): lane owns dims [8L,8L+8) (heads 0..7, 8-lane
// reduce) + dims [512+4L,512+4L+4) (heads 8..11, 16-lane reduce).
// R10: all edge indices preloaded in one coalesced read (cnt <= 64 = wave
// width); per-iter row via __shfl (register). K/V prefetched 2 iterations
// deep — no memory dependency left on the per-edge critical path.
__global__ __launch_bounds__(256) void attn_kernel(const u16* __restrict__ QKV,
                                                   const int* __restrict__ tailrow,
                                                   const int* __restrict__ cursor,
                                                   float* __restrict__ out) {
  __shared__ float sm[2 * 16 * 64];   // [seg-in-block][16 states][64 lanes] = 8 KB
  const int wv = threadIdx.x >> 6;    // 0..3
  const int lane = threadIdx.x & 63;
  const int sIb = wv >> 1;            // segment within block
  const int half = wv & 1;            // which half of the edge list
  const int blk = (blockIdx.x & 7) * (NSEG / 16) + (blockIdx.x >> 3);  // XCD affinity
  const int seg = blk * 2 + sIb;
  const int base = seg * MAXDEG;
  int cnt = cursor[seg];
  if (cnt > MAXDEG) cnt = MAXDEG;
  const int myn = (cnt > half) ? ((cnt - half + 1) >> 1) : 0;   // edges at half, half+2, ...

  // preload ALL edge indices for this segment in one coalesced read
  int myidx = (lane < cnt) ? tailrow[base + lane] : 0;

  // preload q (scaled by 1/sqrt(64)=0.125, exact in f16)
  const u16* qrow = QKV + seg * QKVN;
  __half2 q1[4], q2[2];
  {
    u32x4 qa = *(const u32x4*)(qrow + lane * 8);
    u32x2 qb = *(const u32x2*)(qrow + 512 + lane * 4);
    const __half2 sc = __float2half2_rn(0.125f);
#pragma unroll
    for (int i = 0; i < 4; ++i) q1[i] = __hmul2(h2(qa[i]), sc);
    q2[0] = __hmul2(h2(qb[0]), sc);
    q2[1] = __hmul2(h2(qb[1]), sc);
  }

  float m1 = -__builtin_inff(), l1 = 0.f;
  float m2 = -__builtin_inff(), l2 = 0.f;
  __half2 o1[4] = {}, o2[2] = {};

  auto loadkv = [&](int row, u32x4& k1, u32x2& k2, u32x4& v1, u32x2& v2) {
    const u16* kp = QKV + row * QKVN + HH;
    k1 = *(const u32x4*)(kp + lane * 8);
    k2 = *(const u32x2*)(kp + 512 + lane * 4);
    v1 = *(const u32x4*)(kp + HH + lane * 8);
    v2 = *(const u32x2*)(kp + HH + 512 + lane * 4);
  };

  auto process = [&](u32x4 k1, u32x2 k2, u32x4 v1, u32x2 v2) {
    __half2 a1 = __hmul2(q1[0], h2(k1[0]));
    a1 = __hfma2(q1[1], h2(k1[1]), a1);
    a1 = __hfma2(q1[2], h2(k1[2]), a1);
    a1 = __hfma2(q1[3], h2(k1[3]), a1);
    float s1 = __low2float(a1) + __high2float(a1);
    s1 += __shfl_xor(s1, 1, 64);
    s1 += __shfl_xor(s1, 2, 64);
    s1 += __shfl_xor(s1, 4, 64);
    __half2 a2 = __hmul2(q2[0], h2(k2[0]));
    a2 = __hfma2(q2[1], h2(k2[1]), a2);
    float s2 = __low2float(a2) + __high2float(a2);
    s2 += __shfl_xor(s2, 1, 64);
    s2 += __shfl_xor(s2, 2, 64);
    s2 += __shfl_xor(s2, 4, 64);
    s2 += __shfl_xor(s2, 8, 64);
    {
      float mn = fmaxf(m1, s1);
      float al = __expf(m1 - mn);
      float ex = __expf(s1 - mn);
      l1 = l1 * al + ex;
      __half2 ah = __float2half2_rn(al), eh = __float2half2_rn(ex);
#pragma unroll
      for (int i = 0; i < 4; ++i)
        o1[i] = __hfma2(o1[i], ah, __hmul2(h2(v1[i]), eh));
      m1 = mn;
    }
    {
      float mn = fmaxf(m2, s2);
      float al = __expf(m2 - mn);
      float ex = __expf(s2 - mn);
      l2 = l2 * al + ex;
      __half2 ah = __float2half2_rn(al), eh = __float2half2_rn(ex);
      o2[0] = __hfma2(o2[0], ah, __hmul2(h2(v2[0]), eh));
      o2[1] = __hfma2(o2[1], ah, __hmul2(h2(v2[1]), eh));
      m2 = mn;
    }
  };

  if (myn > 0) {
    u32x4 k1c, v1c, k1n, v1n, k1n2, v1n2;
    u32x2 k2c, v2c, k2n, v2n, k2n2, v2n2;
    loadkv(__shfl(myidx, half, 64), k1c, k2c, v1c, v2c);
    if (myn > 1) loadkv(__shfl(myidx, half + 2, 64), k1n, k2n, v1n, v2n);
    for (int t = 0; t < myn; ++t) {
      if (t + 2 < myn)
        loadkv(__shfl(myidx, half + 2 * (t + 2), 64), k1n2, k2n2, v1n2, v2n2);
      process(k1c, k2c, v1c, v2c);
      k1c = k1n; k2c = k2n; v1c = v1n; v2c = v2n;
      k1n = k1n2; k2n = k2n2; v1n = v1n2; v2n = v2n2;
    }
  }

  // unpack packed accumulators to f32
  float of1[8], of2[4];
#pragma unroll
  for (int i = 0; i < 4; ++i) {
    of1[2 * i] = __low2float(o1[i]);
    of1[2 * i + 1] = __high2float(o1[i]);
  }
#pragma unroll
  for (int i = 0; i < 2; ++i) {
    of2[2 * i] = __low2float(o2[i]);
    of2[2 * i + 1] = __high2float(o2[i]);
  }

  // odd wave publishes its state (state-major: lane-contiguous, conflict-free)
  float* sb = sm + sIb * 16 * 64;
  if (half == 1) {
    sb[0 * 64 + lane] = m1;  sb[1 * 64 + lane] = l1;
    sb[2 * 64 + lane] = m2;  sb[3 * 64 + lane] = l2;
#pragma unroll
    for (int i = 0; i < 8; ++i) sb[(4 + i) * 64 + lane] = of1[i];
#pragma unroll
    for (int i = 0; i < 4; ++i) sb[(12 + i) * 64 + lane] = of2[i];
  }
  __syncthreads();
  if (half == 0) {
    float mB1 = sb[0 * 64 + lane], lB1 = sb[1 * 64 + lane];
    float mB2 = sb[2 * 64 + lane], lB2 = sb[3 * 64 + lane];

    float res1[8], res2[4];
    {
      float mn = fmaxf(fmaxf(m1, mB1), -1e30f);
      float aA = __expf(m1 - mn), aB = __expf(mB1 - mn);
      float l = l1 * aA + lB1 * aB;
      float inv = 1.f / fmaxf(l, 1e-9f);
#pragma unroll
      for (int i = 0; i < 8; ++i)
        res1[i] = (of1[i] * aA + sb[(4 + i) * 64 + lane] * aB) * inv;
    }
    {
      float mn = fmaxf(fmaxf(m2, mB2), -1e30f);
      float aA = __expf(m2 - mn), aB = __expf(mB2 - mn);
      float l = l2 * aA + lB2 * aB;
      float inv = 1.f / fmaxf(l, 1e-9f);
#pragma unroll
      for (int i = 0; i < 4; ++i)
        res2[i] = (of2[i] * aA + sb[(12 + i) * 64 + lane] * aB) * inv;
    }

    float* op = out + seg * HH;
    float4 r0 = {res1[0], res1[1], res1[2], res1[3]};
    float4 r1 = {res1[4], res1[5], res1[6], res1[7]};
    float4 r2 = {res2[0], res2[1], res2[2], res2[3]};
    ((float4*)(op + lane * 8))[0] = r0;
    ((float4*)(op + lane * 8))[1] = r1;
    *(float4*)(op + 512 + lane * 4) = r2;
  }
}

// ---------------- launch ----------------
extern "C" void kernel_launch(void* const* d_in, const int* in_sizes, int n_in,
                              void* d_out, int out_size, void* d_ws, size_t ws_size,
                              hipStream_t stream) {
  const float* X  = (const float*)d_in[0];
  const int*   EI = (const int*)d_in[1];
  const float* Wq = (const float*)d_in[2];
  const float* Wk = (const float*)d_in[3];
  const float* Wv = (const float*)d_in[4];
  float* out = (float*)d_out;
  const int E = in_sizes[1] / 4;

  // workspace layout (~56 MB)
  char* ws = (char*)d_ws;
  int* cursor  = (int*)(ws);                 // 32 KB
  int* tailrow = (int*)(ws + 32768);         // NSEG*64*4 = 2 MB
  u16* Xb      = (u16*)(ws + 2129920);       // 8192*768*2  = 12.6 MB  (f16)
  u16* Wt      = (u16*)(ws + 14712832);      // 2304*768*2  = 3.5 MB   (f16)
  u16* QKV     = (u16*)(ws + 18251776);      // 8192*2304*2 = 37.7 MB  (f16)

  hipMemsetAsync(cursor, 0, NSEG * 4, stream);
  prep_kernel<<<CAST_BLKS + TW_BLKS + BUILD_BLKS, 256, 0, stream>>>(
      X, Xb, Wq, Wk, Wv, Wt, EI, cursor, tailrow, E);
  gemm_kernel<<<(QKVN / BN) * (NSEG / BM), 256, 0, stream>>>(Xb, Wt, QKV);
  attn_kernel<<<NSEG / 2, 256, 0, stream>>>(QKV, tailrow, cursor, out);
}

// Round 11
// 165.977 us; speedup vs baseline: 1.0072x; 1.0072x over previous
//
#include <hip/hip_runtime.h>
#include <hip/hip_fp16.h>

// Problem constants (fixed by reference)
#define BB 8
#define NN 1024
#define HH 768
#define NHEAD 12
#define HD 64
#define NSEG 8192            // B*N
#define QKVN 2304            // 3*H
#define MAXDEG 64            // bucket capacity per segment (Poisson(16); P(>64) ~ 1e-18)

typedef unsigned short u16;
typedef __attribute__((ext_vector_type(8))) _Float16 f16x8;
typedef __attribute__((ext_vector_type(4))) float f32x4;
typedef __attribute__((ext_vector_type(4))) unsigned int u32x4;
typedef __attribute__((ext_vector_type(2))) unsigned int u32x2;

__device__ __forceinline__ u16 f2h(float f) {
  _Float16 h = (_Float16)f;
  return __builtin_bit_cast(u16, h);
}
__device__ __forceinline__ __half2 h2(unsigned int w) {
  return __builtin_bit_cast(__half2, w);
}

// ---------------- fused prep: cast X, transpose W, build CSR ----------------
#define CAST_BLKS (NSEG * HH / 4 / 256)     // 6144
#define TW_BLKS   ((QKVN / 32) * (HH / 32)) // 1728
#define BUILD_BLKS 512

__global__ void prep_kernel(const float* __restrict__ X, u16* __restrict__ Xb,
                            const float* __restrict__ Wq, const float* __restrict__ Wk,
                            const float* __restrict__ Wv, u16* __restrict__ Wt,
                            const int* __restrict__ EI, int* __restrict__ cursor,
                            int* __restrict__ tailrow, int E) {
  const int bid = blockIdx.x;
  if (bid < CAST_BLKS) {
    int i = bid * 256 + threadIdx.x;
    float4 f = ((const float4*)X)[i];
    ushort4 o;
    o.x = f2h(f.x); o.y = f2h(f.y); o.z = f2h(f.z); o.w = f2h(f.w);
    ((ushort4*)Xb)[i] = o;
  } else if (bid < CAST_BLKS + TW_BLKS) {
    __shared__ float tile[32][33];
    int t = bid - CAST_BLKS;
    int n0 = (t % (QKVN / 32)) * 32;
    int k0 = (t / (QKVN / 32)) * 32;
    const float* W = (n0 < HH) ? Wq : (n0 < 2 * HH ? Wk : Wv);
    int nb = n0 - (n0 < HH ? 0 : (n0 < 2 * HH ? HH : 2 * HH));
    int tx = threadIdx.x & 31, ty = threadIdx.x >> 5;   // (32, 8)
#pragma unroll
    for (int r = 0; r < 4; ++r)
      tile[ty + 8 * r][tx] = W[(k0 + ty + 8 * r) * HH + nb + tx];
    __syncthreads();
#pragma unroll
    for (int r = 0; r < 4; ++r)
      Wt[(n0 + ty + 8 * r) * HH + k0 + tx] = f2h(tile[tx][ty + 8 * r]);
  } else {
    int e = (bid - CAST_BLKS - TW_BLKS) * 256 + threadIdx.x;
    if (e >= E) return;
    int b = EI[e];
    int seg = b * NN + EI[E + e];
    int j = EI[2 * E + e];
    int pos = atomicAdd(&cursor[seg], 1);
    if (pos < MAXDEG) tailrow[seg * MAXDEG + pos] = b * NN + j;
  }
}

// ---------------- fused QKV GEMM: (8192x768) @ (768x2304), f16 MFMA ----------------
// (unchanged from R10: depth-2 pipeline, XOR bank-swizzle, XCD m-tile affinity)
#define BM 128
#define BN 128
#define BK 32
#define NITER (HH / BK)   // 24

__global__ __launch_bounds__(256) void gemm_kernel(const u16* __restrict__ Xb,
                                                   const u16* __restrict__ Wt,
                                                   u16* __restrict__ QKV) {
  __shared__ u16 As[3][BM * BK];   // 3 x 8 KB
  __shared__ u16 Bs[3][BN * BK];   // 3 x 8 KB
  const int tid = threadIdx.x;
  const int wave = tid >> 6;
  const int lane = tid & 63;
  const int bid = blockIdx.x;      // 0..1151
  const int mt = (bid & 7) * 8 + ((bid >> 3) & 7);   // m-tile 0..63, XCD-grouped
  const int nt = bid >> 6;                            // n-tile 0..17
  const int m0 = mt * BM;
  const int n0 = nt * BN;
  const int wr = wave >> 1;
  const int wc = wave & 1;
  const int quad = lane >> 4;
  const int l15 = lane & 15;

  f32x4 acc[4][4] = {};

  const int srow = wave * 16 + (lane >> 2);
  const int scol = (((lane & 3) ^ ((lane >> 3) & 3)) << 3);   // swizzled k-quad fetch
  const int rswz = quad ^ ((l15 >> 1) & 3);                    // read-side swizzle

  auto stage = [&](int buf, int kt) {
#pragma unroll
    for (int p = 0; p < 2; ++p) {
      const u16* ga = Xb + (m0 + p * 64 + srow) * HH + kt + scol;
      const u16* gb = Wt + (n0 + p * 64 + srow) * HH + kt + scol;
      u16* la = As[buf] + p * 2048 + wave * 512;
      u16* lb = Bs[buf] + p * 2048 + wave * 512;
      __builtin_amdgcn_global_load_lds(
          (const __attribute__((address_space(1))) unsigned int*)(unsigned long long)ga,
          (__attribute__((address_space(3))) unsigned int*)(unsigned long long)la, 16, 0, 0);
      __builtin_amdgcn_global_load_lds(
          (const __attribute__((address_space(1))) unsigned int*)(unsigned long long)gb,
          (__attribute__((address_space(3))) unsigned int*)(unsigned long long)lb, 16, 0, 0);
    }
  };

  stage(0, 0);
  stage(1, BK);

#pragma unroll 3
  for (int it = 0; it < NITER; ++it) {
    if (it != NITER - 1) {
      asm volatile("s_waitcnt vmcnt(4)" ::: "memory");
    } else {
      asm volatile("s_waitcnt vmcnt(0)" ::: "memory");
    }
    asm volatile("s_barrier" ::: "memory");
    if (it + 2 < NITER) stage((it + 2) % 3, (it + 2) * BK);

    const int b = it % 3;
    f16x8 afr[4], bfr[4];
#pragma unroll
    for (int mi = 0; mi < 4; ++mi) {
      int m = wr * 64 + mi * 16 + l15;
      afr[mi] = *(const f16x8*)(As[b] + m * BK + rswz * 8);
    }
#pragma unroll
    for (int ni = 0; ni < 4; ++ni) {
      int n = wc * 64 + ni * 16 + l15;
      bfr[ni] = *(const f16x8*)(Bs[b] + n * BK + rswz * 8);
    }
#pragma unroll
    for (int mi = 0; mi < 4; ++mi)
#pragma unroll
      for (int ni = 0; ni < 4; ++ni)
        acc[mi][ni] = __builtin_amdgcn_mfma_f32_16x16x32_f16(afr[mi], bfr[ni], acc[mi][ni], 0, 0, 0);
  }

  // epilogue: C/D layout col=lane&15, row=(lane>>4)*4+reg  [m89-verified]
#pragma unroll
  for (int mi = 0; mi < 4; ++mi)
#pragma unroll
    for (int ni = 0; ni < 4; ++ni) {
      int col = n0 + wc * 64 + ni * 16 + l15;
#pragma unroll
      for (int r = 0; r < 4; ++r) {
        int row = m0 + wr * 64 + mi * 16 + quad * 4 + r;
        QKV[row * QKVN + col] = f2h(acc[mi][ni][r]);
      }
    }
}

// ---------------- attention: FOUR waves per segment, LDS merge ----------------
// Lane mapping (R2-verified): lane owns dims [8L,8L+8) (heads 0..7, 8-lane
// reduce) + dims [512+4L,512+4L+4) (heads 8..11, 16-lane reduce).
// R11: one segment per 256-thread block; wave w processes edges w, w+4, ...
// Serial online-softmax chain and straggler tail halve vs the 2-way split
// (R4's mechanism, applied once more). Waves 1..3 publish (m,l,o) to LDS;
// wave 0 merges 4 partials. Idx preload + depth-2 k/v prefetch retained.
__global__ __launch_bounds__(256) void attn_kernel(const u16* __restrict__ QKV,
                                                   const int* __restrict__ tailrow,
                                                   const int* __restrict__ cursor,
                                                   float* __restrict__ out) {
  __shared__ float sm[3 * 16 * 64];   // 12 KB: partial states from waves 1..3
  const int wv = threadIdx.x >> 6;    // 0..3 = edge-stripe
  const int lane = threadIdx.x & 63;
  const int seg = (blockIdx.x & 7) * (NSEG / 8) + (blockIdx.x >> 3);  // XCD affinity: batch = blockIdx&7
  const int base = seg * MAXDEG;
  int cnt = cursor[seg];
  if (cnt > MAXDEG) cnt = MAXDEG;
  const int myn = (cnt > wv) ? ((cnt - wv + 3) >> 2) : 0;   // edges at wv, wv+4, ...

  // preload ALL edge indices for this segment in one coalesced read
  int myidx = (lane < cnt) ? tailrow[base + lane] : 0;

  // preload q (scaled by 1/sqrt(64)=0.125, exact in f16)
  const u16* qrow = QKV + seg * QKVN;
  __half2 q1[4], q2[2];
  {
    u32x4 qa = *(const u32x4*)(qrow + lane * 8);
    u32x2 qb = *(const u32x2*)(qrow + 512 + lane * 4);
    const __half2 sc = __float2half2_rn(0.125f);
#pragma unroll
    for (int i = 0; i < 4; ++i) q1[i] = __hmul2(h2(qa[i]), sc);
    q2[0] = __hmul2(h2(qb[0]), sc);
    q2[1] = __hmul2(h2(qb[1]), sc);
  }

  float m1 = -__builtin_inff(), l1 = 0.f;
  float m2 = -__builtin_inff(), l2 = 0.f;
  __half2 o1[4] = {}, o2[2] = {};

  auto loadkv = [&](int row, u32x4& k1, u32x2& k2, u32x4& v1, u32x2& v2) {
    const u16* kp = QKV + row * QKVN + HH;
    k1 = *(const u32x4*)(kp + lane * 8);
    k2 = *(const u32x2*)(kp + 512 + lane * 4);
    v1 = *(const u32x4*)(kp + HH + lane * 8);
    v2 = *(const u32x2*)(kp + HH + 512 + lane * 4);
  };

  auto process = [&](u32x4 k1, u32x2 k2, u32x4 v1, u32x2 v2) {
    __half2 a1 = __hmul2(q1[0], h2(k1[0]));
    a1 = __hfma2(q1[1], h2(k1[1]), a1);
    a1 = __hfma2(q1[2], h2(k1[2]), a1);
    a1 = __hfma2(q1[3], h2(k1[3]), a1);
    float s1 = __low2float(a1) + __high2float(a1);
    s1 += __shfl_xor(s1, 1, 64);
    s1 += __shfl_xor(s1, 2, 64);
    s1 += __shfl_xor(s1, 4, 64);
    __half2 a2 = __hmul2(q2[0], h2(k2[0]));
    a2 = __hfma2(q2[1], h2(k2[1]), a2);
    float s2 = __low2float(a2) + __high2float(a2);
    s2 += __shfl_xor(s2, 1, 64);
    s2 += __shfl_xor(s2, 2, 64);
    s2 += __shfl_xor(s2, 4, 64);
    s2 += __shfl_xor(s2, 8, 64);
    {
      float mn = fmaxf(m1, s1);
      float al = __expf(m1 - mn);
      float ex = __expf(s1 - mn);
      l1 = l1 * al + ex;
      __half2 ah = __float2half2_rn(al), eh = __float2half2_rn(ex);
#pragma unroll
      for (int i = 0; i < 4; ++i)
        o1[i] = __hfma2(o1[i], ah, __hmul2(h2(v1[i]), eh));
      m1 = mn;
    }
    {
      float mn = fmaxf(m2, s2);
      float al = __expf(m2 - mn);
      float ex = __expf(s2 - mn);
      l2 = l2 * al + ex;
      __half2 ah = __float2half2_rn(al), eh = __float2half2_rn(ex);
      o2[0] = __hfma2(o2[0], ah, __hmul2(h2(v2[0]), eh));
      o2[1] = __hfma2(o2[1], ah, __hmul2(h2(v2[1]), eh));
      m2 = mn;
    }
  };

  if (myn > 0) {
    u32x4 k1c, v1c, k1n, v1n, k1n2, v1n2;
    u32x2 k2c, v2c, k2n, v2n, k2n2, v2n2;
    loadkv(__shfl(myidx, wv, 64), k1c, k2c, v1c, v2c);
    if (myn > 1) loadkv(__shfl(myidx, wv + 4, 64), k1n, k2n, v1n, v2n);
    for (int t = 0; t < myn; ++t) {
      if (t + 2 < myn)
        loadkv(__shfl(myidx, wv + 4 * (t + 2), 64), k1n2, k2n2, v1n2, v2n2);
      process(k1c, k2c, v1c, v2c);
      k1c = k1n; k2c = k2n; v1c = v1n; v2c = v2n;
      k1n = k1n2; k2n = k2n2; v1n = v1n2; v2n = v2n2;
    }
  }

  // unpack packed accumulators to f32
  float of1[8], of2[4];
#pragma unroll
  for (int i = 0; i < 4; ++i) {
    of1[2 * i] = __low2float(o1[i]);
    of1[2 * i + 1] = __high2float(o1[i]);
  }
#pragma unroll
  for (int i = 0; i < 2; ++i) {
    of2[2 * i] = __low2float(o2[i]);
    of2[2 * i + 1] = __high2float(o2[i]);
  }

  // waves 1..3 publish (state-major: lane-contiguous, conflict-free)
  if (wv > 0) {
    float* sb = sm + (wv - 1) * 1024;
    sb[0 * 64 + lane] = m1;  sb[1 * 64 + lane] = l1;
    sb[2 * 64 + lane] = m2;  sb[3 * 64 + lane] = l2;
#pragma unroll
    for (int i = 0; i < 8; ++i) sb[(4 + i) * 64 + lane] = of1[i];
#pragma unroll
    for (int i = 0; i < 4; ++i) sb[(12 + i) * 64 + lane] = of2[i];
  }
  __syncthreads();
  if (wv == 0) {
    // merge 4 partials: own regs + 3 LDS sets
    float mn1 = fmaxf(m1, -1e30f), mn2 = fmaxf(m2, -1e30f);
#pragma unroll
    for (int j = 0; j < 3; ++j) {
      mn1 = fmaxf(mn1, sm[j * 1024 + 0 * 64 + lane]);
      mn2 = fmaxf(mn2, sm[j * 1024 + 2 * 64 + lane]);
    }
    float res1[8], res2[4];
    {
      float a0 = __expf(m1 - mn1);
      float l = l1 * a0;
#pragma unroll
      for (int i = 0; i < 8; ++i) res1[i] = of1[i] * a0;
#pragma unroll
      for (int j = 0; j < 3; ++j) {
        const float* sb = sm + j * 1024;
        float aj = __expf(sb[0 * 64 + lane] - mn1);
        l += sb[1 * 64 + lane] * aj;
#pragma unroll
        for (int i = 0; i < 8; ++i) res1[i] += sb[(4 + i) * 64 + lane] * aj;
      }
      float inv = 1.f / fmaxf(l, 1e-9f);
#pragma unroll
      for (int i = 0; i < 8; ++i) res1[i] *= inv;
    }
    {
      float a0 = __expf(m2 - mn2);
      float l = l2 * a0;
#pragma unroll
      for (int i = 0; i < 4; ++i) res2[i] = of2[i] * a0;
#pragma unroll
      for (int j = 0; j < 3; ++j) {
        const float* sb = sm + j * 1024;
        float aj = __expf(sb[2 * 64 + lane] - mn2);
        l += sb[3 * 64 + lane] * aj;
#pragma unroll
        for (int i = 0; i < 4; ++i) res2[i] += sb[(12 + i) * 64 + lane] * aj;
      }
      float inv = 1.f / fmaxf(l, 1e-9f);
#pragma unroll
      for (int i = 0; i < 4; ++i) res2[i] *= inv;
    }

    float* op = out + seg * HH;
    float4 r0 = {res1[0], res1[1], res1[2], res1[3]};
    float4 r1 = {res1[4], res1[5], res1[6], res1[7]};
    float4 r2 = {res2[0], res2[1], res2[2], res2[3]};
    ((float4*)(op + lane * 8))[0] = r0;
    ((float4*)(op + lane * 8))[1] = r1;
    *(float4*)(op + 512 + lane * 4) = r2;
  }
}

// ---------------- launch ----------------
extern "C" void kernel_launch(void* const* d_in, const int* in_sizes, int n_in,
                              void* d_out, int out_size, void* d_ws, size_t ws_size,
                              hipStream_t stream) {
  const float* X  = (const float*)d_in[0];
  const int*   EI = (const int*)d_in[1];
  const float* Wq = (const float*)d_in[2];
  const float* Wk = (const float*)d_in[3];
  const float* Wv = (const float*)d_in[4];
  float* out = (float*)d_out;
  const int E = in_sizes[1] / 4;

  // workspace layout (~56 MB)
  char* ws = (char*)d_ws;
  int* cursor  = (int*)(ws);                 // 32 KB
  int* tailrow = (int*)(ws + 32768);         // NSEG*64*4 = 2 MB
  u16* Xb      = (u16*)(ws + 2129920);       // 8192*768*2  = 12.6 MB  (f16)
  u16* Wt      = (u16*)(ws + 14712832);      // 2304*768*2  = 3.5 MB   (f16)
  u16* QKV     = (u16*)(ws + 18251776);      // 8192*2304*2 = 37.7 MB  (f16)

  hipMemsetAsync(cursor, 0, NSEG * 4, stream);
  prep_kernel<<<CAST_BLKS + TW_BLKS + BUILD_BLKS, 256, 0, stream>>>(
      X, Xb, Wq, Wk, Wv, Wt, EI, cursor, tailrow, E);
  gemm_kernel<<<(QKVN / BN) * (NSEG / BM), 256, 0, stream>>>(Xb, Wt, QKV);
  attn_kernel<<<NSEG, 256, 0, stream>>>(QKV, tailrow, cursor, out);
}